// Round 1
// baseline (651.991 us; speedup 1.0000x reference)
//
#include <hip/hip_runtime.h>
#include <hip/hip_bf16.h>

typedef __bf16 bf16x8 __attribute__((ext_vector_type(8)));
typedef float  floatx4 __attribute__((ext_vector_type(4)));

#define LSTR 72   // LDS row stride (elements): 144 B/row, 16B-aligned fragments, breaks pow2 banks

enum { EPI_PROJ = 0, EPI_SCORES = 1, EPI_CTX = 2, EPI_OUT = 3 };

// Stage a 64(row) x 64(col) tile from row-major global (row stride ld) into
// LDS laid out [row][col] with stride LSTR, converting to bf16.
template <class T>
__device__ __forceinline__ void stage_rm(__bf16* dst, const T* src, int ld, int tid) {
  if constexpr (sizeof(T) == 4) {          // fp32 source: float4 vector loads
#pragma unroll
    for (int i = 0; i < 4; i++) {
      int c   = i * 256 + tid;             // 1024 float4 chunks
      int row = c >> 4;                    // 16 chunks per 64-elem row
      int c4  = c & 15;
      const float4 v = *(const float4*)((const float*)src + (size_t)row * ld + c4 * 4);
      __bf16* d = dst + row * LSTR + c4 * 4;
      d[0] = (__bf16)v.x; d[1] = (__bf16)v.y; d[2] = (__bf16)v.z; d[3] = (__bf16)v.w;
    }
  } else {                                  // bf16 source: 16B vector loads
#pragma unroll
    for (int i = 0; i < 2; i++) {
      int c   = i * 256 + tid;             // 512 8-elem chunks
      int row = c >> 3;
      int c8  = c & 7;
      bf16x8 v = *(const bf16x8*)((const __bf16*)src + (size_t)row * ld + c8 * 8);
      *(bf16x8*)(dst + row * LSTR + c8 * 8) = v;
    }
  }
}

// Stage a 64(k) x 64(n) tile from row-major K x N global into LDS transposed
// as [n][k] (stride LSTR). Coalesced global reads, scalar LDS writes.
template <class T>
__device__ __forceinline__ void stage_tr(__bf16* dst, const T* src, int ld, int tid) {
#pragma unroll
  for (int i = 0; i < 16; i++) {
    int e = i * 256 + tid;                 // 4096 elements
    int k = e >> 6;
    int n = e & 63;
    if constexpr (sizeof(T) == 4)
      dst[n * LSTR + k] = (__bf16)((const float*)src)[(size_t)k * ld + n];
    else
      dst[n * LSTR + k] = ((const __bf16*)src)[(size_t)k * ld + n];
  }
}

// C = A * B (+bias / +mask+scale), 64x64 block tile, 4 waves, each wave owns a
// 16-row strip x 64 cols (4 MFMA n-tiles). 16x16x32 bf16 MFMA, fp32 accum.
// BNT: B stored N x K (row-major) -> stage like A. else B stored K x N -> transpose-stage.
template <class TA, class TB, bool BNT, int EPI>
__global__ __launch_bounds__(256) void gemm_k(
    const TA* __restrict__ Ag, const TB* __restrict__ Bg,
    const float* __restrict__ bias, void* __restrict__ Cv,
    const int* __restrict__ mask,
    int M, int N, int Kd, int lda, int ldb, int ldc,
    long long sA, long long sB, long long sC, long long sM, float scale) {
  const int bz = blockIdx.z;
  Ag += (size_t)bz * sA;
  Bg += (size_t)bz * sB;
  const int* mp = nullptr;
  if (EPI == EPI_SCORES) mp = mask + (size_t)bz * sM;

  const int m0 = blockIdx.y * 64;
  const int n0 = blockIdx.x * 64;

  __shared__ __bf16 As[64 * LSTR];
  __shared__ __bf16 Bs[64 * LSTR];

  const int tid  = threadIdx.x;
  const int lane = tid & 63;
  const int w    = tid >> 6;
  const int lo   = lane & 15;
  const int quad = lane >> 4;

  floatx4 acc[4];
#pragma unroll
  for (int i = 0; i < 4; i++) acc[i] = (floatx4){0.f, 0.f, 0.f, 0.f};

  for (int kk = 0; kk < Kd; kk += 64) {
    stage_rm<TA>(As, Ag + (size_t)m0 * lda + kk, lda, tid);
    if (BNT) stage_rm<TB>(Bs, Bg + (size_t)n0 * ldb + kk, ldb, tid);
    else     stage_tr<TB>(Bs, Bg + (size_t)kk * ldb + n0, ldb, tid);
    __syncthreads();
#pragma unroll
    for (int kq = 0; kq < 2; kq++) {
      bf16x8 a = *(const bf16x8*)&As[(w * 16 + lo) * LSTR + kq * 32 + quad * 8];
#pragma unroll
      for (int nt = 0; nt < 4; nt++) {
        bf16x8 b = *(const bf16x8*)&Bs[(nt * 16 + lo) * LSTR + kq * 32 + quad * 8];
        acc[nt] = __builtin_amdgcn_mfma_f32_16x16x32_bf16(a, b, acc[nt], 0, 0, 0);
      }
    }
    __syncthreads();
  }

  // Epilogue. C/D layout (m89-verified): col = lane&15, row = (lane>>4)*4 + r
#pragma unroll
  for (int nt = 0; nt < 4; nt++) {
    int gn = n0 + nt * 16 + lo;
#pragma unroll
    for (int r = 0; r < 4; r++) {
      int gm = m0 + w * 16 + quad * 4 + r;
      float v = acc[nt][r];
      size_t ci = (size_t)bz * sC + (size_t)gm * ldc + gn;
      if (EPI == EPI_PROJ) {
        ((__bf16*)Cv)[ci] = (__bf16)(v + bias[gn]);
      } else if (EPI == EPI_SCORES) {
        float s = v * scale;
        if (mp[(size_t)gm * ldc + gn] != 0) s = 1e-20f;
        ((float*)Cv)[ci] = s;
      } else if (EPI == EPI_CTX) {
        ((__bf16*)Cv)[ci] = (__bf16)v;
      } else {  // EPI_OUT
        ((float*)Cv)[ci] = v + bias[gn];
      }
    }
  }
}

// Row softmax over S=2048 fp32 scores -> bf16 attn. One 256-thread block per row.
__global__ __launch_bounds__(256) void softmax_k(const float* __restrict__ Sc,
                                                 __bf16* __restrict__ Ab, int S) {
  const size_t row = blockIdx.x;
  const float* p = Sc + row * S;
  __bf16* o = Ab + row * S;
  const int tid = threadIdx.x;

  float v[8];
  float m = -1e30f;
#pragma unroll
  for (int i = 0; i < 8; i++) { v[i] = p[tid + i * 256]; m = fmaxf(m, v[i]); }
#pragma unroll
  for (int off = 32; off; off >>= 1) m = fmaxf(m, __shfl_xor(m, off, 64));
  __shared__ float redm[4];
  const int wv = tid >> 6;
  if ((tid & 63) == 0) redm[wv] = m;
  __syncthreads();
  m = fmaxf(fmaxf(redm[0], redm[1]), fmaxf(redm[2], redm[3]));

  float s = 0.f;
#pragma unroll
  for (int i = 0; i < 8; i++) { v[i] = __expf(v[i] - m); s += v[i]; }
#pragma unroll
  for (int off = 32; off; off >>= 1) s += __shfl_xor(s, off, 64);
  __shared__ float reds[4];
  if ((tid & 63) == 0) reds[wv] = s;
  __syncthreads();
  s = reds[0] + reds[1] + reds[2] + reds[3];
  const float inv = 1.0f / s;
#pragma unroll
  for (int i = 0; i < 8; i++) o[tid + i * 256] = (__bf16)(v[i] * inv);
}

extern "C" void kernel_launch(void* const* d_in, const int* in_sizes, int n_in,
                              void* d_out, int out_size, void* d_ws, size_t ws_size,
                              hipStream_t stream) {
  (void)in_sizes; (void)n_in; (void)out_size; (void)ws_size;
  const int B = 4, S = 2048, H = 1024;
  const int MS = B * S;  // 8192

  const float* X    = (const float*)d_in[0];
  const int*   msk  = (const int*)d_in[1];
  const float* Wq   = (const float*)d_in[2];
  const float* bq   = (const float*)d_in[3];
  const float* Wk   = (const float*)d_in[4];
  const float* bk   = (const float*)d_in[5];
  const float* Wv   = (const float*)d_in[6];
  const float* bv   = (const float*)d_in[7];
  const float* Wo   = (const float*)d_in[8];
  const float* bo   = (const float*)d_in[9];
  float* out = (float*)d_out;

  // Workspace layout (128 MiB total):
  //   Qb[16M] Kb[16M] Vb[16M] Cx[16M] Sc[64M fp32]
  //   Ab (attn bf16, 32M) aliases Qb+Kb (dead after the scores GEMM).
  char* ws = (char*)d_ws;
  __bf16* Qb = (__bf16*)ws;
  __bf16* Kb = Qb + (size_t)MS * H;
  __bf16* Vb = Kb + (size_t)MS * H;
  __bf16* Cx = Vb + (size_t)MS * H;
  float*  Sc = (float*)(Cx + (size_t)MS * H);
  __bf16* Ab = (__bf16*)ws;

  dim3 blk(256);

  // Q/K/V projections: [8192x1024] = X[8192x1024] @ W[1024x1024] + b  -> bf16
  gemm_k<float, float, false, EPI_PROJ><<<dim3(H / 64, MS / 64, 1), blk, 0, stream>>>(
      X, Wq, bq, Qb, nullptr, MS, H, H, H, H, H, 0, 0, 0, 0, 0.f);
  gemm_k<float, float, false, EPI_PROJ><<<dim3(H / 64, MS / 64, 1), blk, 0, stream>>>(
      X, Wk, bk, Kb, nullptr, MS, H, H, H, H, H, 0, 0, 0, 0, 0.f);
  gemm_k<float, float, false, EPI_PROJ><<<dim3(H / 64, MS / 64, 1), blk, 0, stream>>>(
      X, Wv, bv, Vb, nullptr, MS, H, H, H, H, H, 0, 0, 0, 0, 0.f);

  // Scores: per batch [2048x2048] = Q @ K^T, scaled 1/32, mask -> 1e-20  -> fp32
  gemm_k<__bf16, __bf16, true, EPI_SCORES><<<dim3(S / 64, S / 64, B), blk, 0, stream>>>(
      Qb, Kb, nullptr, Sc, msk, S, S, H, H, H, S,
      (long long)S * H, (long long)S * H, (long long)S * S, (long long)S * S, 0.03125f);

  // Softmax rows -> bf16 attn (aliases dead Q/K region)
  softmax_k<<<dim3(B * S, 1, 1), blk, 0, stream>>>(Sc, Ab, S);

  // ctx: per batch [2048x1024] = attn[2048x2048] @ V[2048x1024] -> bf16
  gemm_k<__bf16, __bf16, false, EPI_CTX><<<dim3(H / 64, S / 64, B), blk, 0, stream>>>(
      Ab, Vb, nullptr, Cx, nullptr, S, H, S, S, H, H,
      (long long)S * S, (long long)S * H, (long long)S * H, 0, 0.f);

  // out: [8192x1024] = Cx @ Wo + bo -> fp32 d_out
  gemm_k<__bf16, float, false, EPI_OUT><<<dim3(H / 64, MS / 64, 1), blk, 0, stream>>>(
      Cx, Wo, bo, out, nullptr, MS, H, H, H, H, H, 0, 0, 0, 0, 0.f);
}

// Round 2
// 392.311 us; speedup vs baseline: 1.6619x; 1.6619x over previous
//
#include <hip/hip_runtime.h>
#include <hip/hip_bf16.h>

typedef __bf16 bf16x8 __attribute__((ext_vector_type(8)));
typedef __bf16 bf16x4 __attribute__((ext_vector_type(4)));
typedef float  floatx4 __attribute__((ext_vector_type(4)));

enum { EPI_PROJ = 0, EPI_PROJVT = 1, EPI_SCORES = 2, EPI_CTX = 3, EPI_OUT = 4 };

// Async global->LDS, 16 B per lane. LDS dest must be wave-uniform base;
// lane i deposits at base + i*16 (m97 pattern — no padding possible).
#define GLOAD16(gp, lp)                                                        \
  __builtin_amdgcn_global_load_lds(                                            \
      (const __attribute__((address_space(1))) void*)(gp),                     \
      (__attribute__((address_space(3))) void*)(lp), 16, 0, 0)

// ---------------------------------------------------------------------------
// 128x128 tile GEMM, BK=64, 256 threads (4 waves, 2x2 of 64x64 per wave),
// 16x16x32 bf16 MFMA, fp32 accum. A: M x K row-major bf16. B: N x K row-major
// bf16 ("B^T" form). Epilogue variants per EPI.
// ---------------------------------------------------------------------------
template <int EPI>
__global__ __launch_bounds__(256) void gemm128(
    const __bf16* __restrict__ Ag, const __bf16* __restrict__ Bg,
    const float* __restrict__ bias, void* __restrict__ Cv,
    const int* __restrict__ mask,
    int Kd, int lda, int ldb, int ldc,
    long long sA, long long sB, long long sC, long long sM, float scale) {
  const int bz = blockIdx.z;
  const __bf16* A = Ag + (size_t)bz * sA;
  const __bf16* Bp = Bg + (size_t)bz * sB;
  const int m0 = blockIdx.y * 128;
  const int n0 = blockIdx.x * 128;

  __shared__ __bf16 As[128 * 64];
  __shared__ __bf16 Bs[128 * 64];

  const int tid  = threadIdx.x;
  const int lane = tid & 63;
  const int w    = tid >> 6;
  const int lo   = lane & 15;
  const int quad = lane >> 4;
  const int lrow  = lane >> 3;        // staging: row within 8-row group
  const int lcol8 = (lane & 7) * 8;   // staging: 8-elem (16 B) column chunk

  floatx4 acc[4][4];
#pragma unroll
  for (int mt = 0; mt < 4; mt++)
#pragma unroll
    for (int nt = 0; nt < 4; nt++) acc[mt][nt] = (floatx4){0.f, 0.f, 0.f, 0.f};

  // Each wave stages rows [w*32, w*32+32) of both tiles: 4 insts x 8 rows.
  const __bf16* aptr = A + (size_t)(m0 + w * 32 + lrow) * lda + lcol8;
  const __bf16* bptr = Bp + (size_t)(n0 + w * 32 + lrow) * ldb + lcol8;
  __bf16* asl = As + (w * 32) * 64;   // wave-uniform LDS bases
  __bf16* bsl = Bs + (w * 32) * 64;

  for (int kk = 0; kk < Kd; kk += 64) {
#pragma unroll
    for (int i = 0; i < 4; i++) {
      GLOAD16(aptr + (size_t)(i * 8) * lda + kk, asl + i * 8 * 64);
      GLOAD16(bptr + (size_t)(i * 8) * ldb + kk, bsl + i * 8 * 64);
    }
    __syncthreads();   // drains vmcnt: staging visible
#pragma unroll
    for (int kq = 0; kq < 2; kq++) {
      bf16x8 af[4], bfq[4];
#pragma unroll
      for (int mt = 0; mt < 4; mt++)
        af[mt] = *(const bf16x8*)&As[((w >> 1) * 64 + mt * 16 + lo) * 64 + kq * 32 + quad * 8];
#pragma unroll
      for (int nt = 0; nt < 4; nt++)
        bfq[nt] = *(const bf16x8*)&Bs[((w & 1) * 64 + nt * 16 + lo) * 64 + kq * 32 + quad * 8];
#pragma unroll
      for (int mt = 0; mt < 4; mt++)
#pragma unroll
        for (int nt = 0; nt < 4; nt++)
          acc[mt][nt] = __builtin_amdgcn_mfma_f32_16x16x32_bf16(af[mt], bfq[nt], acc[mt][nt], 0, 0, 0);
    }
    __syncthreads();   // compute done before next overwrite
  }

  // Epilogue. C/D layout (m89): col = lane&15, row = (lane>>4)*4 + r.
#pragma unroll
  for (int mt = 0; mt < 4; mt++) {
    const int gmb = m0 + (w >> 1) * 64 + mt * 16 + quad * 4;
#pragma unroll
    for (int nt = 0; nt < 4; nt++) {
      const int gn = n0 + (w & 1) * 64 + nt * 16 + lo;
      if (EPI == EPI_PROJVT) {
        // V projection written transposed: Vt[b2][gn][sm..sm+3], packed 8 B.
        const int b2 = gmb >> 11, sm = gmb & 2047;
        const float bv_ = bias[gn];
        bf16x4 pk;
#pragma unroll
        for (int r = 0; r < 4; r++) pk[r] = (__bf16)(acc[mt][nt][r] + bv_);
        *(bf16x4*)((__bf16*)Cv + ((size_t)b2 * 1024 + gn) * 2048 + sm) = pk;
      } else {
#pragma unroll
        for (int r = 0; r < 4; r++) {
          const int gm = gmb + r;
          const float v = acc[mt][nt][r];
          const size_t ci = (size_t)bz * sC + (size_t)gm * ldc + gn;
          if (EPI == EPI_PROJ) {
            ((__bf16*)Cv)[ci] = (__bf16)(v + bias[gn]);
          } else if (EPI == EPI_SCORES) {
            float s = v * scale;
            if (mask[(size_t)bz * sM + (size_t)gm * ldc + gn] != 0) s = 1e-20f;
            ((__bf16*)Cv)[ci] = (__bf16)s;
          } else if (EPI == EPI_CTX) {
            ((__bf16*)Cv)[ci] = (__bf16)v;
          } else {  // EPI_OUT
            ((float*)Cv)[ci] = v + bias[gn];
          }
        }
      }
    }
  }
}

// Convert fp32 X -> bf16, 4 elems/thread (float4 in, 8 B out).
__global__ __launch_bounds__(256) void cvtx_k(const float* __restrict__ X,
                                              __bf16* __restrict__ Xb) {
  const size_t i = (size_t)blockIdx.x * 256 + threadIdx.x;
  const float4 v = ((const float4*)X)[i];
  bf16x4 o;
  o[0] = (__bf16)v.x; o[1] = (__bf16)v.y; o[2] = (__bf16)v.z; o[3] = (__bf16)v.w;
  ((bf16x4*)Xb)[i] = o;
}

// Fused transpose+convert of the 4 weight matrices (1024x1024 fp32 K x N)
// into bf16 N x K at Wt + z*1M. 64x64 tiles through padded LDS.
__global__ __launch_bounds__(256) void wtrans_k(
    const float* __restrict__ Wq, const float* __restrict__ Wk,
    const float* __restrict__ Wv, const float* __restrict__ Wo,
    __bf16* __restrict__ Wt) {
  const int z = blockIdx.z;
  const float* W = (z == 0) ? Wq : (z == 1) ? Wk : (z == 2) ? Wv : Wo;
  __bf16* D = Wt + (size_t)z * 1024 * 1024;
  __shared__ float T[64][65];
  const int r0 = blockIdx.y * 64, c0 = blockIdx.x * 64;
#pragma unroll
  for (int i = 0; i < 16; i++) {
    const int e = i * 256 + threadIdx.x;
    const int r = e >> 6, c = e & 63;
    T[r][c] = W[(size_t)(r0 + r) * 1024 + c0 + c];
  }
  __syncthreads();
#pragma unroll
  for (int i = 0; i < 16; i++) {
    const int e = i * 256 + threadIdx.x;
    const int rr = e >> 6, cc = e & 63;   // rr = output row (orig col)
    D[(size_t)(c0 + rr) * 1024 + r0 + cc] = (__bf16)T[cc][rr];
  }
}

// Row softmax over S=2048 bf16 scores -> bf16 attn. One block per row,
// 8 contiguous elements per thread (16 B vector loads/stores).
__global__ __launch_bounds__(256) void softmax_k(const __bf16* __restrict__ Sc,
                                                 __bf16* __restrict__ Ab, int S) {
  const size_t row = blockIdx.x;
  const __bf16* p = Sc + row * S;
  __bf16* o = Ab + row * S;
  const int tid = threadIdx.x;

  const bf16x8 raw = *(const bf16x8*)(p + tid * 8);
  float v[8];
  float m = -1e30f;
#pragma unroll
  for (int i = 0; i < 8; i++) { v[i] = (float)raw[i]; m = fmaxf(m, v[i]); }
#pragma unroll
  for (int off = 32; off; off >>= 1) m = fmaxf(m, __shfl_xor(m, off, 64));
  __shared__ float redm[4], reds[4];
  const int wv = tid >> 6;
  if ((tid & 63) == 0) redm[wv] = m;
  __syncthreads();
  m = fmaxf(fmaxf(redm[0], redm[1]), fmaxf(redm[2], redm[3]));

  float s = 0.f;
#pragma unroll
  for (int i = 0; i < 8; i++) { v[i] = __expf(v[i] - m); s += v[i]; }
#pragma unroll
  for (int off = 32; off; off >>= 1) s += __shfl_xor(s, off, 64);
  if ((tid & 63) == 0) reds[wv] = s;
  __syncthreads();
  s = reds[0] + reds[1] + reds[2] + reds[3];
  const float inv = 1.0f / s;
  bf16x8 ov;
#pragma unroll
  for (int i = 0; i < 8; i++) ov[i] = (__bf16)(v[i] * inv);
  *(bf16x8*)(o + tid * 8) = ov;
}

extern "C" void kernel_launch(void* const* d_in, const int* in_sizes, int n_in,
                              void* d_out, int out_size, void* d_ws, size_t ws_size,
                              hipStream_t stream) {
  (void)in_sizes; (void)n_in; (void)out_size; (void)ws_size;
  const int B = 4, S = 2048, H = 1024;
  const int MS = B * S;  // 8192

  const float* X   = (const float*)d_in[0];
  const int*   msk = (const int*)d_in[1];
  const float* Wq  = (const float*)d_in[2];
  const float* bq  = (const float*)d_in[3];
  const float* Wk  = (const float*)d_in[4];
  const float* bk  = (const float*)d_in[5];
  const float* Wv  = (const float*)d_in[6];
  const float* bv  = (const float*)d_in[7];
  const float* Wo  = (const float*)d_in[8];
  const float* bo  = (const float*)d_in[9];
  float* out = (float*)d_out;

  // Workspace (distinct regions ~109 MB; known >= ~134 MB from round 1):
  //   Xb[16.8M] Wt[8.4M] Qb[16.8M] Kb[16.8M] Vt[16.8M] Sc[33.6M bf16]
  //   Ab (attn, 33.6M) aliases Qb+Kb (dead after scores GEMM).
  //   Cx (ctx, 16.8M) aliases Xb (dead after projections).
  char* ws = (char*)d_ws;
  __bf16* Xb = (__bf16*)ws;
  __bf16* Wt = Xb + (size_t)MS * H;
  __bf16* Qb = Wt + (size_t)4 * H * H;
  __bf16* Kb = Qb + (size_t)MS * H;
  __bf16* Vt = Kb + (size_t)MS * H;
  __bf16* Sc = Vt + (size_t)MS * H;
  __bf16* Ab = Qb;   // alias
  __bf16* Cx = Xb;   // alias

  dim3 blk(256);

  cvtx_k<<<dim3(MS * H / 4 / 256), blk, 0, stream>>>(X, Xb);
  wtrans_k<<<dim3(16, 16, 4), blk, 0, stream>>>(Wq, Wk, Wv, Wo, Wt);

  // Projections: [8192x1024] = Xb @ Wt^T(+b). grid (N/128, M/128).
  gemm128<EPI_PROJ><<<dim3(H / 128, MS / 128, 1), blk, 0, stream>>>(
      Xb, Wt + (size_t)0 * H * H, bq, Qb, nullptr, H, H, H, H, 0, 0, 0, 0, 0.f);
  gemm128<EPI_PROJ><<<dim3(H / 128, MS / 128, 1), blk, 0, stream>>>(
      Xb, Wt + (size_t)1 * H * H, bk, Kb, nullptr, H, H, H, H, 0, 0, 0, 0, 0.f);
  gemm128<EPI_PROJVT><<<dim3(H / 128, MS / 128, 1), blk, 0, stream>>>(
      Xb, Wt + (size_t)2 * H * H, bv, Vt, nullptr, H, H, H, H, 0, 0, 0, 0, 0.f);

  // Scores: per batch [2048x2048] = Q @ K^T / 32, mask -> 1e-20, bf16 out.
  gemm128<EPI_SCORES><<<dim3(S / 128, S / 128, B), blk, 0, stream>>>(
      Qb, Kb, nullptr, Sc, msk, H, H, H, S,
      (long long)S * H, (long long)S * H, (long long)S * S, (long long)S * S, 0.03125f);

  softmax_k<<<dim3(B * S), blk, 0, stream>>>(Sc, Ab, S);

  // ctx: per batch [2048x1024] = attn @ Vt^T. A row stride S, B (Vt) N x K.
  gemm128<EPI_CTX><<<dim3(H / 128, S / 128, B), blk, 0, stream>>>(
      Ab, Vt, nullptr, Cx, nullptr, S, S, S, H,
      (long long)S * S, (long long)H * S, (long long)S * H, 0, 0.f);

  // out: [8192x1024] = Cx @ Wo^T + bo -> fp32 d_out.
  gemm128<EPI_OUT><<<dim3(H / 128, MS / 128, 1), blk, 0, stream>>>(
      Cx, Wt + (size_t)3 * H * H, bo, out, nullptr, H, H, H, H, 0, 0, 0, 0, 0.f);
}

// Round 3
// 381.687 us; speedup vs baseline: 1.7082x; 1.0278x over previous
//
#include <hip/hip_runtime.h>
#include <hip/hip_bf16.h>

typedef __bf16 bf16x8 __attribute__((ext_vector_type(8)));
typedef __bf16 bf16x4 __attribute__((ext_vector_type(4)));
typedef float  floatx4 __attribute__((ext_vector_type(4)));

enum { EPI_QKV = 0, EPI_EXP = 1, EPI_CTX = 2, EPI_OUT = 3 };

#define MSH 8388608ll  // 8192*1024, Q/K/V plane stride in the fused epilogue

// Async global->LDS, 16 B per lane. LDS dest is wave-uniform base + lane*16.
#define GLOAD16(gp, lp)                                                        \
  __builtin_amdgcn_global_load_lds(                                            \
      (const __attribute__((address_space(1))) void*)(gp),                     \
      (__attribute__((address_space(3))) void*)(lp), 16, 0, 0)

// ---------------------------------------------------------------------------
// 128x128 tile GEMM, BK=64, 256 threads (4 waves, each owns a 64x64 quadrant
// as 4x4 MFMA tiles), 16x16x32 bf16 MFMA, fp32 accum.
// A: M x K row-major bf16. B: N x K row-major bf16.
// EPI_QKV : N=3072 fused projection; cols 0-1023 -> Q(+b0), 1024-2047 ->
//           K(+b1) row-major; 2048-3071 -> V(+b2) written TRANSPOSED.
// EPI_EXP : E = exp(mask ? 1e-20 : v*scale) -> bf16; rowsum atomics into Lbuf.
// EPI_CTX : v / Lbuf[row] -> bf16.
// EPI_OUT : v + b0 -> fp32.
// ---------------------------------------------------------------------------
template <int EPI>
__global__ __launch_bounds__(256) void gemm128(
    const __bf16* __restrict__ Ag, const __bf16* __restrict__ Bg,
    const float* __restrict__ b0, const float* __restrict__ b1,
    const float* __restrict__ b2, void* __restrict__ Cv,
    const int* __restrict__ mask, float* __restrict__ Lbuf,
    int Kd, int lda, int ldb, int ldc,
    long long sA, long long sB, long long sC, long long sM, float scale) {
  const int bz = blockIdx.z;
  const __bf16* A  = Ag + (size_t)bz * sA;
  const __bf16* Bp = Bg + (size_t)bz * sB;
  const int m0 = blockIdx.y * 128;
  const int n0 = blockIdx.x * 128;

  __shared__ __bf16 As[128 * 64];
  __shared__ __bf16 Bs[128 * 64];

  const int tid  = threadIdx.x;
  const int lane = tid & 63;
  const int w    = tid >> 6;
  const int lo   = lane & 15;
  const int quad = lane >> 4;
  const int lrow  = lane >> 3;        // staging: row within 8-row group
  const int lcol8 = (lane & 7) * 8;   // staging: 8-elem (16 B) column chunk

  floatx4 acc[4][4];
#pragma unroll
  for (int mt = 0; mt < 4; mt++)
#pragma unroll
    for (int nt = 0; nt < 4; nt++) acc[mt][nt] = (floatx4){0.f, 0.f, 0.f, 0.f};

  const __bf16* aptr = A + (size_t)(m0 + w * 32 + lrow) * lda + lcol8;
  const __bf16* bptr = Bp + (size_t)(n0 + w * 32 + lrow) * ldb + lcol8;
  __bf16* asl = As + (w * 32) * 64;
  __bf16* bsl = Bs + (w * 32) * 64;

  for (int kk = 0; kk < Kd; kk += 64) {
#pragma unroll
    for (int i = 0; i < 4; i++) {
      GLOAD16(aptr + (size_t)(i * 8) * lda + kk, asl + i * 8 * 64);
      GLOAD16(bptr + (size_t)(i * 8) * ldb + kk, bsl + i * 8 * 64);
    }
    __syncthreads();
#pragma unroll
    for (int kq = 0; kq < 2; kq++) {
      bf16x8 af[4], bfq[4];
#pragma unroll
      for (int mt = 0; mt < 4; mt++)
        af[mt] = *(const bf16x8*)&As[((w >> 1) * 64 + mt * 16 + lo) * 64 + kq * 32 + quad * 8];
#pragma unroll
      for (int nt = 0; nt < 4; nt++)
        bfq[nt] = *(const bf16x8*)&Bs[((w & 1) * 64 + nt * 16 + lo) * 64 + kq * 32 + quad * 8];
#pragma unroll
      for (int mt = 0; mt < 4; mt++)
#pragma unroll
        for (int nt = 0; nt < 4; nt++)
          acc[mt][nt] = __builtin_amdgcn_mfma_f32_16x16x32_bf16(af[mt], bfq[nt], acc[mt][nt], 0, 0, 0);
    }
    __syncthreads();
  }

  // Epilogue. C/D layout (m89): col = lane&15, row = (lane>>4)*4 + r.
  if (EPI == EPI_QKV) {
    const int which = n0 >> 10;  // 0=Q 1=K 2=V (block-uniform; 1024%128==0)
    const float* bp = (which == 0) ? b0 : (which == 1) ? b1 : b2;
#pragma unroll
    for (int mt = 0; mt < 4; mt++) {
      const int gmb = m0 + (w >> 1) * 64 + mt * 16 + quad * 4;
#pragma unroll
      for (int nt = 0; nt < 4; nt++) {
        const int gn  = n0 + (w & 1) * 64 + nt * 16 + lo;
        const int gnl = gn & 1023;
        const float bv_ = bp[gnl];
        if (which == 2) {
          // V transposed: Vt[b2][gnl][sm..sm+3], packed 8 B.
          const int bb = gmb >> 11, sm = gmb & 2047;
          bf16x4 pk;
#pragma unroll
          for (int r = 0; r < 4; r++) pk[r] = (__bf16)(acc[mt][nt][r] + bv_);
          *(bf16x4*)((__bf16*)Cv + 2 * MSH + ((size_t)bb * 1024 + gnl) * 2048 + sm) = pk;
        } else {
#pragma unroll
          for (int r = 0; r < 4; r++)
            ((__bf16*)Cv)[(size_t)which * MSH + (size_t)(gmb + r) * 1024 + gnl] =
                (__bf16)(acc[mt][nt][r] + bv_);
        }
      }
    }
  } else if (EPI == EPI_EXP) {
#pragma unroll
    for (int mt = 0; mt < 4; mt++) {
      const int gmb = m0 + (w >> 1) * 64 + mt * 16 + quad * 4;
#pragma unroll
      for (int r = 0; r < 4; r++) {
        const int gm = gmb + r;
        float rowpart = 0.f;
#pragma unroll
        for (int nt = 0; nt < 4; nt++) {
          const int gn = n0 + (w & 1) * 64 + nt * 16 + lo;
          float s = acc[mt][nt][r] * scale;
          if (mask[(size_t)bz * sM + (size_t)gm * ldc + gn] != 0) s = 1e-20f;
          const float e = __expf(s);
          rowpart += e;
          ((__bf16*)Cv)[(size_t)bz * sC + (size_t)gm * ldc + gn] = (__bf16)e;
        }
        rowpart += __shfl_xor(rowpart, 1);
        rowpart += __shfl_xor(rowpart, 2);
        rowpart += __shfl_xor(rowpart, 4);
        rowpart += __shfl_xor(rowpart, 8);
        if (lo == 0) atomicAdd(&Lbuf[(size_t)bz * 2048 + gm], rowpart);
      }
    }
  } else {
#pragma unroll
    for (int mt = 0; mt < 4; mt++) {
      const int gmb = m0 + (w >> 1) * 64 + mt * 16 + quad * 4;
#pragma unroll
      for (int nt = 0; nt < 4; nt++) {
        const int gn = n0 + (w & 1) * 64 + nt * 16 + lo;
#pragma unroll
        for (int r = 0; r < 4; r++) {
          const int gm = gmb + r;
          const size_t ci = (size_t)bz * sC + (size_t)gm * ldc + gn;
          if (EPI == EPI_CTX) {
            const float inv = 1.0f / Lbuf[(size_t)bz * 2048 + gm];
            ((__bf16*)Cv)[ci] = (__bf16)(acc[mt][nt][r] * inv);
          } else {  // EPI_OUT
            ((float*)Cv)[ci] = acc[mt][nt][r] + b0[gn];
          }
        }
      }
    }
  }
}

// Convert fp32 X -> bf16, 4 elems/thread.
__global__ __launch_bounds__(256) void cvtx_k(const float* __restrict__ X,
                                              __bf16* __restrict__ Xb) {
  const size_t i = (size_t)blockIdx.x * 256 + threadIdx.x;
  const float4 v = ((const float4*)X)[i];
  bf16x4 o;
  o[0] = (__bf16)v.x; o[1] = (__bf16)v.y; o[2] = (__bf16)v.z; o[3] = (__bf16)v.w;
  ((bf16x4*)Xb)[i] = o;
}

// Transpose+convert the 4 weight matrices (1024x1024 fp32 K x N) into bf16
// N x K at Wt + z*1M (q,k,v,o order -> rows 0-4095 of the combined buffer).
__global__ __launch_bounds__(256) void wtrans_k(
    const float* __restrict__ Wq, const float* __restrict__ Wk,
    const float* __restrict__ Wv, const float* __restrict__ Wo,
    __bf16* __restrict__ Wt) {
  const int z = blockIdx.z;
  const float* W = (z == 0) ? Wq : (z == 1) ? Wk : (z == 2) ? Wv : Wo;
  __bf16* D = Wt + (size_t)z * 1024 * 1024;
  __shared__ float T[64][65];
  const int r0 = blockIdx.y * 64, c0 = blockIdx.x * 64;
#pragma unroll
  for (int i = 0; i < 16; i++) {
    const int e = i * 256 + threadIdx.x;
    const int r = e >> 6, c = e & 63;
    T[r][c] = W[(size_t)(r0 + r) * 1024 + c0 + c];
  }
  __syncthreads();
#pragma unroll
  for (int i = 0; i < 16; i++) {
    const int e = i * 256 + threadIdx.x;
    const int rr = e >> 6, cc = e & 63;
    D[(size_t)(c0 + rr) * 1024 + r0 + cc] = (__bf16)T[cc][rr];
  }
}

extern "C" void kernel_launch(void* const* d_in, const int* in_sizes, int n_in,
                              void* d_out, int out_size, void* d_ws, size_t ws_size,
                              hipStream_t stream) {
  (void)in_sizes; (void)n_in; (void)out_size; (void)ws_size;
  const int B = 4, S = 2048, H = 1024;
  const int MS = B * S;  // 8192

  const float* X   = (const float*)d_in[0];
  const int*   msk = (const int*)d_in[1];
  const float* Wq  = (const float*)d_in[2];
  const float* bq  = (const float*)d_in[3];
  const float* Wk  = (const float*)d_in[4];
  const float* bk  = (const float*)d_in[5];
  const float* Wv  = (const float*)d_in[6];
  const float* bv  = (const float*)d_in[7];
  const float* Wo  = (const float*)d_in[8];
  const float* bo  = (const float*)d_in[9];
  float* out = (float*)d_out;

  // Workspace (~109.2 MB):
  //   Xb[16.8M] Wt[8.4M] Qb[16.8M] Kb[16.8M] Vt[16.8M] E[33.6M bf16] L[32K]
  //   Cx (ctx, 16.8M) aliases Xb (dead after QKV projection).
  char* ws = (char*)d_ws;
  __bf16* Xb = (__bf16*)ws;
  __bf16* Wt = Xb + (size_t)MS * H;
  __bf16* Qb = Wt + (size_t)4 * H * H;   // Q,K,Vt contiguous (QKV epilogue)
  __bf16* Kb = Qb + (size_t)MS * H;
  __bf16* Vt = Kb + (size_t)MS * H;
  __bf16* E  = Vt + (size_t)MS * H;
  float*  L  = (float*)(E + (size_t)B * S * S);
  __bf16* Cx = Xb;  // alias

  dim3 blk(256);

  hipMemsetAsync(L, 0, (size_t)B * S * sizeof(float), stream);
  cvtx_k<<<dim3(MS * H / 4 / 256), blk, 0, stream>>>(X, Xb);
  wtrans_k<<<dim3(16, 16, 4), blk, 0, stream>>>(Wq, Wk, Wv, Wo, Wt);

  // Fused QKV projection: [8192 x 3072] = Xb @ Wt[0:3072]^T (+biases).
  gemm128<EPI_QKV><<<dim3(3 * H / 128, MS / 128, 1), blk, 0, stream>>>(
      Xb, Wt, bq, bk, bv, Qb, nullptr, nullptr,
      H, H, H, H, 0, 0, 0, 0, 0.f);

  // Scores -> E = exp(mask ? 1e-20 : QK^T/32) bf16, rowsums into L.
  gemm128<EPI_EXP><<<dim3(S / 128, S / 128, B), blk, 0, stream>>>(
      Qb, Kb, nullptr, nullptr, nullptr, E, msk, L,
      H, H, H, S, (long long)S * H, (long long)S * H,
      (long long)S * S, (long long)S * S, 0.03125f);

  // ctx: per batch [2048x1024] = (E @ Vt^T) / L -> bf16.
  gemm128<EPI_CTX><<<dim3(H / 128, S / 128, B), blk, 0, stream>>>(
      E, Vt, nullptr, nullptr, nullptr, Cx, nullptr, L,
      S, S, S, H, (long long)S * S, (long long)H * S, (long long)S * H, 0, 0.f);

  // out: [8192x1024] = Cx @ Wo^T + bo -> fp32.
  gemm128<EPI_OUT><<<dim3(H / 128, MS / 128, 1), blk, 0, stream>>>(
      Cx, Wt + (size_t)3 * H * H, bo, nullptr, nullptr, out, nullptr, nullptr,
      H, H, H, H, 0, 0, 0, 0, 0.f);
}